// Round 4
// baseline (5261.240 us; speedup 1.0000x reference)
//
#include <hip/hip_runtime.h>
#include <stdint.h>

#define BB 256
#define TT 128
#define DD 512
#define HH 512
#define G4 2048      // 4H
#define BH (BB*HH)

typedef short bf16x8 __attribute__((ext_vector_type(8)));
typedef unsigned short u16x8 __attribute__((ext_vector_type(8)));
typedef float f32x4  __attribute__((ext_vector_type(4)));

__device__ __forceinline__ unsigned short f2bf(float f){
  union { float f; unsigned u; } v; v.f = f;
  unsigned u = v.u;
  unsigned r = (u + 0x7FFFu + ((u >> 16) & 1u)) >> 16;
  return (unsigned short)r;
}
__device__ __forceinline__ float bf2f(unsigned short s){
  union { unsigned u; float f; } v; v.u = ((unsigned)s) << 16;
  return v.f;
}
__device__ __forceinline__ float sigf(float x){
  return __builtin_amdgcn_rcpf(1.0f + __expf(-x));
}
__device__ __forceinline__ float tanhfast(float x){
  return 1.0f - 2.0f*__builtin_amdgcn_rcpf(1.0f + __expf(2.0f*x));
}

// x [B,T,D] f32 -> xtr [T,B,D] bf16
__global__ void prep_x_k(const float* __restrict__ x, unsigned short* __restrict__ xtr){
  const int n4 = BB*TT*(DD/4);
  for (int i = blockIdx.x*blockDim.x + threadIdx.x; i < n4; i += gridDim.x*blockDim.x){
    int d4 = i & (DD/4 - 1);
    int b  = (i / (DD/4)) & (BB-1);
    int t  = i / ((DD/4)*BB);
    float4 v = *(const float4*)(x + (((size_t)b*TT + t)*DD + (size_t)d4*4));
    ushort4 o;
    o.x = f2bf(v.x); o.y = f2bf(v.y); o.z = f2bf(v.z); o.w = f2bf(v.w);
    *(ushort4*)(xtr + (((size_t)t*BB + b)*DD + (size_t)d4*4)) = o;
  }
}

// Wp[d][n'][k] bf16, n' = hb*64 + g*16 + j <-> orig col n = g*512 + hb*16 + j
__global__ void prep_w_k(const float* __restrict__ Wf, const float* __restrict__ Wb,
                         unsigned short* __restrict__ wp){
  const int tot = 2*G4*DD;  // 2M
  for (int i = blockIdx.x*blockDim.x + threadIdx.x; i < tot; i += gridDim.x*blockDim.x){
    int k  = i & 511;
    int np = (i >> 9) & 2047;
    int d  = i >> 20;
    int j = np & 15, g = (np>>4)&3, hb = np>>6;
    int n = g*HH + hb*16 + j;
    const float* W = d ? Wb : Wf;
    wp[i] = f2bf(W[(size_t)k*G4 + n]);
  }
}

// Upack[d][nh][w][ks][nt][lane][8] bf16  (fragment-packed for phase-2 B-operand)
__global__ void prep_u_k(const float* __restrict__ Uf, const float* __restrict__ Ub,
                         unsigned short* __restrict__ up){
  const int tot = 2*2*8*16*8*64*8;  // 2M
  for (int i = blockIdx.x*blockDim.x + threadIdx.x; i < tot; i += gridDim.x*blockDim.x){
    int e    = i & 7;
    int lane = (i>>3) & 63;
    int nt   = (i>>9) & 7;
    int ks   = (i>>12) & 15;
    int w    = (i>>16) & 7;
    int nh   = (i>>19) & 1;
    int d    = (i>>20) & 1;
    int jl = lane & 15, q = lane >> 4;
    int np = nh*1024 + w*128 + nt*16 + jl;
    int k  = ks*32 + q*8 + e;
    int j = np & 15, g = (np>>4)&3, hb = np>>6;
    int n = g*HH + hb*16 + j;
    const float* U = d ? Ub : Uf;
    up[i] = f2bf(U[(size_t)k*G4 + n]);
  }
}

__global__ void prep_bias_k(const float* __restrict__ bf_, const float* __restrict__ bb_,
                            float* __restrict__ bias_pk){
  int i = blockIdx.x*blockDim.x + threadIdx.x;
  if (i < 2*G4){
    int np = i & (G4-1);
    int d  = i >> 11;
    int j = np & 15, g = (np>>4)&3, hb = np>>6;
    const float* src = d ? bb_ : bf_;
    bias_pk[i] = src[g*HH + hb*16 + j];
  }
}

// Phase 1: zx = x.W + b for all t, both dirs. 4096 blocks x 512 thr.
// bid: mt = bid&255 (128 rows of [T*B]), nt8 = (bid>>8)&7 (256 cols), d = bid>>11.
// Output packed per phase-2 consumer fragment layout:
// zxp[d][t][rg16][nh][w][chunk4][lane64][8 bf16]
__global__ __launch_bounds__(512, 1)
void gemm_xw_k(const unsigned short* __restrict__ xtr,
               const unsigned short* __restrict__ wp,
               const float* __restrict__ bias_pk,
               unsigned short* __restrict__ zxp)
{
  __shared__ __align__(1024) unsigned short Ax[2][128*64];
  __shared__ __align__(1024) unsigned short Bx[2][256*64];
  const int tid = threadIdx.x, lane = tid & 63, w = tid >> 6;
  const int bid = blockIdx.x;
  const int mt  = bid & 255;
  const int nt8 = (bid >> 8) & 7;
  const int d   = bid >> 11;
  const int gm = w >> 2, gn = w & 3;
  const int jl = lane & 15, q = lane >> 4;

  const unsigned short* Asrc = xtr + (size_t)mt*128*DD;
  const unsigned short* Bsrc = wp + ((size_t)d*G4 + nt8*256)*DD;

  auto stage = [&](int kc, int bufi){
    #pragma unroll
    for (int i = 0; i < 2; ++i){
      int u = i*512 + tid;
      int row = u >> 3, uu = u & 7, su = uu ^ (row & 7);
      __builtin_amdgcn_global_load_lds(
        (const __attribute__((address_space(1))) void*)(Asrc + (size_t)row*DD + kc*64 + su*8),
        (__attribute__((address_space(3))) void*)(&Ax[bufi][u*8]), 16, 0, 0);
    }
    #pragma unroll
    for (int i = 0; i < 4; ++i){
      int u = i*512 + tid;
      int row = u >> 3, uu = u & 7, su = uu ^ (row & 7);
      __builtin_amdgcn_global_load_lds(
        (const __attribute__((address_space(1))) void*)(Bsrc + (size_t)row*DD + kc*64 + su*8),
        (__attribute__((address_space(3))) void*)(&Bx[bufi][u*8]), 16, 0, 0);
    }
  };

  f32x4 acc[4][4];
  #pragma unroll
  for (int a = 0; a < 4; ++a)
    #pragma unroll
    for (int b = 0; b < 4; ++b) acc[a][b] = (f32x4){0.f,0.f,0.f,0.f};

  stage(0, 0);
  __syncthreads();
  for (int kc = 0; kc < 8; ++kc){
    int cb = kc & 1;
    if (kc < 7) stage(kc+1, cb^1);
    #pragma unroll
    for (int ksl = 0; ksl < 2; ++ksl){
      bf16x8 a[4], b[4];
      #pragma unroll
      for (int am = 0; am < 4; ++am){
        int row = gm*64 + am*16 + jl;
        int uu = (ksl*4 + q) ^ (row & 7);
        a[am] = *(const bf16x8*)(&Ax[cb][row*64 + uu*8]);
      }
      #pragma unroll
      for (int an = 0; an < 4; ++an){
        int row = gn*64 + an*16 + jl;
        int uu = (ksl*4 + q) ^ (row & 7);
        b[an] = *(const bf16x8*)(&Bx[cb][row*64 + uu*8]);
      }
      #pragma unroll
      for (int am = 0; am < 4; ++am)
        #pragma unroll
        for (int an = 0; an < 4; ++an)
          acc[am][an] = __builtin_amdgcn_mfma_f32_16x16x32_bf16(a[am], b[an], acc[am][an], 0, 0, 0);
    }
    __syncthreads();
  }

  // epilogue: add bias, pack into consumer fragment layout
  const int t = mt >> 1, bhalf = mt & 1;
  const int nh = nt8 >> 2;
  const int wc = (nt8*2 + (gn >> 1)) & 7;
  float bv[4];
  #pragma unroll
  for (int an = 0; an < 4; ++an)
    bv[an] = bias_pk[d*G4 + nt8*256 + gn*64 + an*16 + jl];

  #pragma unroll
  for (int am = 0; am < 4; ++am){
    int rg = bhalf*8 + gm*4 + am;
    #pragma unroll
    for (int a = 0; a < 2; ++a){
      u16x8 pk;
      #pragma unroll
      for (int rr = 0; rr < 4; ++rr){
        pk[rr]     = f2bf(acc[am][2*a][rr]   + bv[2*a]);
        pk[4 + rr] = f2bf(acc[am][2*a+1][rr] + bv[2*a+1]);
      }
      int chunk = (gn & 1)*2 + a;
      size_t off = (((((size_t)d*TT + t)*16 + rg)*2 + nh)*8 + wc)*4 + chunk;
      *(u16x8*)(zxp + off*512 + lane*8) = pk;
    }
  }
}

// Phase 2: persistent step loop. 64 blocks x 512 thr (8 waves), block-local recurrence.
// bid: d = bid>>5, r = (bid>>1)&15 (16 batch rows), nh = bid&1 (1024 gate-cols).
// Pairwise h-half exchange with partner (d, r, 1-nh) via agent-scope hx + flag.
__global__ __launch_bounds__(512, 1)
void lstm_seq_k(const unsigned short* __restrict__ zxp,
                const unsigned short* __restrict__ upack,
                unsigned short* hx,
                int* hxflag,
                float* __restrict__ out)
{
  __shared__ __align__(1024) unsigned short hlds[2][16*256];  // own h-half, swizzled

  const int tid  = threadIdx.x;
  const int lane = tid & 63;
  const int w    = tid >> 6;
  const int bid  = blockIdx.x;
  const int d    = bid >> 5;
  const int r    = (bid >> 1) & 15;
  const int nh   = bid & 1;
  const int jl   = lane & 15, q = lane >> 4;

  // zero both h parities (h0 = 0)
  {
    int* hi = (int*)&hlds[0][0];
    for (int i = tid; i < 16*256; i += 512) hi[i] = 0;
  }

  const unsigned short* myU = upack + (((size_t)d*2 + nh)*8 + w) * 65536; // [ks16][nt8][512 u16]
  const int* pflag = hxflag + (((d*16 + r)*2 + (1 - nh)) << 6);
  const unsigned short* pbase0 = hx + ((((size_t)(d*16 + r)*2 + (1 - nh))*2)*16)*256;
  unsigned short* obase0 = hx + ((((size_t)(d*16 + r)*2 + nh)*2)*16)*256;

  float cst[2][4];
  #pragma unroll
  for (int a = 0; a < 2; ++a)
    #pragma unroll
    for (int b = 0; b < 4; ++b) cst[a][b] = 0.f;

  __syncthreads();

  for (int s = 0; s < TT; ++s){
    const int t = d ? (TT-1-s) : s;
    const int par = s & 1;

    // zx fragments for this step (plain loads; independent of recurrence)
    const unsigned short* zbase =
        zxp + ((((((size_t)d*TT + t)*16 + r)*2 + nh)*8 + w)*4)*512 + lane*8;
    u16x8 zc[4];
    #pragma unroll
    for (int c = 0; c < 4; ++c) zc[c] = *(const u16x8*)(zbase + c*512);

    // wait for partner h^{(s)} (stored at end of its step s-1)
    if (s > 0){
      while (__hip_atomic_load(pflag, __ATOMIC_RELAXED, __HIP_MEMORY_SCOPE_AGENT) < s) {}
    }
    asm volatile("" ::: "memory");

    // partner A-fragments (16 rows x 256 cols, agent-scope loads)
    const unsigned short* pb = pbase0 + (size_t)par*16*256;
    unsigned long long pa0[8], pa1[8];
    #pragma unroll
    for (int p = 0; p < 8; ++p){
      const unsigned long long* pp = (const unsigned long long*)(pb + (size_t)jl*256 + p*32 + q*8);
      pa0[p] = __hip_atomic_load(pp,     __ATOMIC_RELAXED, __HIP_MEMORY_SCOPE_AGENT);
      pa1[p] = __hip_atomic_load(pp + 1, __ATOMIC_RELAXED, __HIP_MEMORY_SCOPE_AGENT);
    }

    f32x4 acc[8];
    #pragma unroll
    for (int nt = 0; nt < 8; ++nt) acc[nt] = (f32x4){0.f,0.f,0.f,0.f};

    // own half first (A from LDS) — hides partner load latency
    #pragma unroll
    for (int p = 0; p < 8; ++p){
      int ba = (jl*512 + p*64 + q*16) ^ ((jl & 7) << 4);
      bf16x8 a = *(const bf16x8*)((const char*)&hlds[par][0] + ba);
      int ks = nh*8 + p;
      #pragma unroll
      for (int nt = 0; nt < 8; ++nt){
        const bf16x8* bp = (const bf16x8*)(myU + ((size_t)ks*8 + nt)*512 + lane*8);
        acc[nt] = __builtin_amdgcn_mfma_f32_16x16x32_bf16(a, *bp, acc[nt], 0, 0, 0);
      }
    }
    // partner half
    #pragma unroll
    for (int p = 0; p < 8; ++p){
      union { unsigned long long u[2]; bf16x8 v; } af;
      af.u[0] = pa0[p]; af.u[1] = pa1[p];
      int ks = (1 - nh)*8 + p;
      #pragma unroll
      for (int nt = 0; nt < 8; ++nt){
        const bf16x8* bp = (const bf16x8*)(myU + ((size_t)ks*8 + nt)*512 + lane*8);
        acc[nt] = __builtin_amdgcn_mfma_f32_16x16x32_bf16(af.v, *bp, acc[nt], 0, 0, 0);
      }
    }

    // epilogue: z = acc + zx; gates; c,h; write h (LDS + partner hx + out)
    unsigned short* ob = obase0 + (size_t)((s+1)&1)*16*256;
    #pragma unroll
    for (int hbp = 0; hbp < 2; ++hbp){
      #pragma unroll
      for (int rr = 0; rr < 4; ++rr){
        float zi = acc[hbp*4+0][rr] + bf2f((unsigned short)zc[hbp*2  ][rr]);
        float zf = acc[hbp*4+1][rr] + bf2f((unsigned short)zc[hbp*2  ][4+rr]);
        float zg = acc[hbp*4+2][rr] + bf2f((unsigned short)zc[hbp*2+1][rr]);
        float zo = acc[hbp*4+3][rr] + bf2f((unsigned short)zc[hbp*2+1][4+rr]);
        float i_ = sigf(zi);
        float f_ = sigf(zf);
        float g_ = tanhfast(zg);
        float o_ = sigf(zo);
        float c  = f_*cst[hbp][rr] + i_*g_;
        cst[hbp][rr] = c;
        float h = o_*tanhfast(c);

        int row = q*4 + rr;
        int col = w*32 + hbp*16 + jl;
        // LDS for own next-step A-frags (swizzled)
        int ba = (row*512 + col*2) ^ ((row & 7) << 4);
        *(unsigned short*)((char*)&hlds[(s+1)&1][0] + ba) = f2bf(h);
        // global hx for partner (packed pairs, agent scope)
        unsigned short h16 = f2bf(h);
        int other = __shfl_xor((int)h16, 1);
        if (!(jl & 1)){
          unsigned int pack = (unsigned int)h16 | (((unsigned int)other & 0xFFFFu) << 16);
          __hip_atomic_store((unsigned int*)(ob + (size_t)row*256 + (col & ~1)),
                             pack, __ATOMIC_RELAXED, __HIP_MEMORY_SCOPE_AGENT);
        }
        // word_emb output
        int b = r*16 + row;
        out[((size_t)b*TT + t)*(2*HH) + (size_t)d*HH + nh*256 + col] = h;
      }
    }

    __syncthreads();   // drains each wave's vmcnt; hlds writes visible
    if (tid == 0)
      __hip_atomic_store(hxflag + (((d*16 + r)*2 + nh) << 6), s + 1,
                         __ATOMIC_RELAXED, __HIP_MEMORY_SCOPE_AGENT);
  }
}

// sent_emb[b][n] = word_emb[b][T-1][n] (n<H) or word_emb[b][0][n] (n>=H)
__global__ void final_k(float* __restrict__ out){
  int i = blockIdx.x*blockDim.x + threadIdx.x;
  if (i < BB*2*HH){
    int b = i >> 10;
    int n = i & 1023;
    int t = (n < HH) ? (TT-1) : 0;
    out[(size_t)BB*TT*2*HH + i] = out[((size_t)b*TT + t)*2*HH + n];
  }
}

extern "C" void kernel_launch(void* const* d_in, const int* in_sizes, int n_in,
                              void* d_out, int out_size, void* d_ws, size_t ws_size,
                              hipStream_t stream)
{
  const float* x   = (const float*)d_in[0];
  const float* Wf  = (const float*)d_in[1];
  const float* Uf  = (const float*)d_in[2];
  const float* bf_ = (const float*)d_in[3];
  const float* Wb  = (const float*)d_in[4];
  const float* Ub  = (const float*)d_in[5];
  const float* bb_ = (const float*)d_in[6];
  float* out = (float*)d_out;

  char* ws = (char*)d_ws;
  unsigned short* xtr   = (unsigned short*)(ws);              // 33,554,432 B
  unsigned short* wp    = (unsigned short*)(ws + 33554432);   //  4,194,304 B
  unsigned short* upack = (unsigned short*)(ws + 37748736);   //  4,194,304 B
  float* bias_pk        = (float*)(ws + 41943040);            //     16,384 B
  unsigned short* hx    = (unsigned short*)(ws + 41959424);   //  1,048,576 B
  int* hxflag           = (int*)(ws + 43008000);              //     16,384 B
  unsigned short* zxp   = (unsigned short*)(ws + 50331648);   // 268,435,456 B

  hipMemsetAsync(hx, 0, 1048576, stream);
  hipMemsetAsync(hxflag, 0, 16384, stream);

  prep_x_k   <<<2048, 256, 0, stream>>>(x, xtr);
  prep_w_k   <<<2048, 256, 0, stream>>>(Wf, Wb, wp);
  prep_u_k   <<<2048, 256, 0, stream>>>(Uf, Ub, upack);
  prep_bias_k<<<16,   256, 0, stream>>>(bf_, bb_, bias_pk);

  gemm_xw_k<<<4096, 512, 0, stream>>>(xtr, wp, bias_pk, zxp);

  void* kargs[] = {(void*)&zxp, (void*)&upack, (void*)&hx, (void*)&hxflag, (void*)&out};
  hipLaunchCooperativeKernel((const void*)lstm_seq_k, dim3(64), dim3(512),
                             kargs, 0, stream);

  final_k<<<1024, 256, 0, stream>>>(out);
}

// Round 5
// 807.168 us; speedup vs baseline: 6.5181x; 6.5181x over previous
//
#include <hip/hip_runtime.h>
#include <stdint.h>

#define BB 256
#define TT 128
#define DD 512
#define HH 512
#define G4 2048      // 4H
#define BH (BB*HH)

typedef short bf16x8 __attribute__((ext_vector_type(8)));
typedef unsigned short u16x8 __attribute__((ext_vector_type(8)));
typedef float f32x4  __attribute__((ext_vector_type(4)));

__device__ __forceinline__ unsigned short f2bf(float f){
  union { float f; unsigned u; } v; v.f = f;
  unsigned u = v.u;
  unsigned r = (u + 0x7FFFu + ((u >> 16) & 1u)) >> 16;
  return (unsigned short)r;
}
__device__ __forceinline__ float bf2f(unsigned short s){
  union { unsigned u; float f; } v; v.u = ((unsigned)s) << 16;
  return v.f;
}
__device__ __forceinline__ float sigf(float x){
  return __builtin_amdgcn_rcpf(1.0f + __expf(-x));
}
__device__ __forceinline__ float tanhfast(float x){
  return 1.0f - 2.0f*__builtin_amdgcn_rcpf(1.0f + __expf(2.0f*x));
}

// x [B,T,D] f32 -> xtr [T,B,D] bf16
__global__ void prep_x_k(const float* __restrict__ x, unsigned short* __restrict__ xtr){
  const int n4 = BB*TT*(DD/4);
  for (int i = blockIdx.x*blockDim.x + threadIdx.x; i < n4; i += gridDim.x*blockDim.x){
    int d4 = i & (DD/4 - 1);
    int b  = (i / (DD/4)) & (BB-1);
    int t  = i / ((DD/4)*BB);
    float4 v = *(const float4*)(x + (((size_t)b*TT + t)*DD + (size_t)d4*4));
    ushort4 o;
    o.x = f2bf(v.x); o.y = f2bf(v.y); o.z = f2bf(v.z); o.w = f2bf(v.w);
    *(ushort4*)(xtr + (((size_t)t*BB + b)*DD + (size_t)d4*4)) = o;
  }
}

// Wp[d][n'][k] bf16 (k<512), n' = hb*64 + g*16 + j <-> orig col n = g*512 + hb*16 + j
__global__ void prep_w_k(const float* __restrict__ Wf, const float* __restrict__ Wb,
                         unsigned short* __restrict__ wp){
  const int tot = 2*G4*DD;
  for (int i = blockIdx.x*blockDim.x + threadIdx.x; i < tot; i += gridDim.x*blockDim.x){
    int k  = i & 511;
    int np = (i >> 9) & 2047;
    int d  = i >> 20;
    int j = np & 15, g = (np>>4)&3, hb = np>>6;
    int n = g*HH + hb*16 + j;
    const float* W = d ? Wb : Wf;
    wp[i] = f2bf(W[(size_t)k*G4 + n]);
  }
}

// Upk[d][hb(32)][ks(16)][gf(4)][lane(64)][e(8)] bf16 — B-fragment order for phase 2
__global__ void prep_u_k(const float* __restrict__ Uf, const float* __restrict__ Ub,
                         unsigned short* __restrict__ up){
  const int tot = 2*32*16*4*64*8;  // 2M
  for (int i = blockIdx.x*blockDim.x + threadIdx.x; i < tot; i += gridDim.x*blockDim.x){
    int e    = i & 7;
    int lane = (i>>3) & 63;
    int gf   = (i>>9) & 3;
    int ks   = (i>>11) & 15;
    int hb   = (i>>15) & 31;
    int d    = (i>>20) & 1;
    int jl = lane & 15, q = lane >> 4;
    int n  = gf*HH + hb*16 + jl;
    int k  = ks*32 + q*8 + e;
    const float* U = d ? Ub : Uf;
    up[i] = f2bf(U[(size_t)k*G4 + n]);
  }
}

__global__ void prep_bias_k(const float* __restrict__ bf_, const float* __restrict__ bb_,
                            float* __restrict__ bias_pk){
  int i = blockIdx.x*blockDim.x + threadIdx.x;
  if (i < 2*G4){
    int np = i & (G4-1);
    int d  = i >> 11;
    int j = np & 15, g = (np>>4)&3, hb = np>>6;
    const float* src = d ? bb_ : bf_;
    bias_pk[i] = src[g*HH + hb*16 + j];
  }
}

// Phase 1: zx = x.W + b for all t, both dirs. 4096 blocks x 512 thr.
// Output packed in phase-2 consumer fragment order:
// zxp[d][t][mq(4)][hb(32)][wc(4)][lane(64)][16] bf16, elem = gate*4 + rr
__global__ __launch_bounds__(512, 1)
void gemm_xw_k(const unsigned short* __restrict__ xtr,
               const unsigned short* __restrict__ wp,
               const float* __restrict__ bias_pk,
               unsigned short* __restrict__ zxp)
{
  __shared__ __align__(1024) unsigned short Ax[2][128*64];
  __shared__ __align__(1024) unsigned short Bx[2][256*64];
  const int tid = threadIdx.x, lane = tid & 63, w = tid >> 6;
  const int bid = blockIdx.x;
  const int mt  = bid & 255;
  const int nt8 = (bid >> 8) & 7;
  const int d   = bid >> 11;
  const int gm = w >> 2, gn = w & 3;
  const int jl = lane & 15, q = lane >> 4;

  const unsigned short* Asrc = xtr + (size_t)mt*128*DD;
  const unsigned short* Bsrc = wp + ((size_t)d*G4 + nt8*256)*DD;

  auto stage = [&](int kc, int bufi){
    #pragma unroll
    for (int i = 0; i < 2; ++i){
      int u = i*512 + tid;
      int row = u >> 3, uu = u & 7, su = uu ^ (row & 7);
      __builtin_amdgcn_global_load_lds(
        (const __attribute__((address_space(1))) void*)(Asrc + (size_t)row*DD + kc*64 + su*8),
        (__attribute__((address_space(3))) void*)(&Ax[bufi][u*8]), 16, 0, 0);
    }
    #pragma unroll
    for (int i = 0; i < 4; ++i){
      int u = i*512 + tid;
      int row = u >> 3, uu = u & 7, su = uu ^ (row & 7);
      __builtin_amdgcn_global_load_lds(
        (const __attribute__((address_space(1))) void*)(Bsrc + (size_t)row*DD + kc*64 + su*8),
        (__attribute__((address_space(3))) void*)(&Bx[bufi][u*8]), 16, 0, 0);
    }
  };

  f32x4 acc[4][4];
  #pragma unroll
  for (int a = 0; a < 4; ++a)
    #pragma unroll
    for (int b = 0; b < 4; ++b) acc[a][b] = (f32x4){0.f,0.f,0.f,0.f};

  stage(0, 0);
  __syncthreads();
  for (int kc = 0; kc < 8; ++kc){
    int cb = kc & 1;
    if (kc < 7) stage(kc+1, cb^1);
    #pragma unroll
    for (int ksl = 0; ksl < 2; ++ksl){
      bf16x8 a[4], b[4];
      #pragma unroll
      for (int am = 0; am < 4; ++am){
        int row = gm*64 + am*16 + jl;
        int uu = (ksl*4 + q) ^ (row & 7);
        a[am] = *(const bf16x8*)(&Ax[cb][row*64 + uu*8]);
      }
      #pragma unroll
      for (int an = 0; an < 4; ++an){
        int row = gn*64 + an*16 + jl;
        int uu = (ksl*4 + q) ^ (row & 7);
        b[an] = *(const bf16x8*)(&Bx[cb][row*64 + uu*8]);
      }
      #pragma unroll
      for (int am = 0; am < 4; ++am)
        #pragma unroll
        for (int an = 0; an < 4; ++an)
          acc[am][an] = __builtin_amdgcn_mfma_f32_16x16x32_bf16(a[am], b[an], acc[am][an], 0, 0, 0);
    }
    __syncthreads();
  }

  // epilogue: add bias, pack into consumer layout
  const int t  = mt >> 1;
  const int mq = (mt & 1)*2 + gm;
  const int hb = nt8*4 + gn;
  float bv[4];
  #pragma unroll
  for (int an = 0; an < 4; ++an)
    bv[an] = bias_pk[d*G4 + nt8*256 + gn*64 + an*16 + jl];

  #pragma unroll
  for (int am = 0; am < 4; ++am){
    size_t base = (((((size_t)d*TT + t)*4 + mq)*32 + hb)*4 + am)*64 + (q*16 + jl);
    #pragma unroll
    for (int gg = 0; gg < 2; ++gg){
      u16x8 pk;
      #pragma unroll
      for (int rr = 0; rr < 4; ++rr){
        pk[rr]   = f2bf(acc[am][2*gg  ][rr] + bv[2*gg  ]);
        pk[4+rr] = f2bf(acc[am][2*gg+1][rr] + bv[2*gg+1]);
      }
      *(u16x8*)(zxp + base*16 + gg*8) = pk;
    }
  }
}

// Phase 2: persistent step loop, XCD-grouped N-tiling.
// 256 blocks x 256 thr (4 waves). g = bid&7 -> (d = g>>2, mq = g&3); hb = bid>>3.
// Block owns gate-cols n' in [hb*64, hb*64+64) for batch rows [mq*64, mq*64+64).
// U slice (64KB) resident in LDS. Per step: 2KB h-chunk store, 32-flag exchange.
__global__ __launch_bounds__(256, 1)
void lstm_seq_k(const unsigned short* __restrict__ zxp,
                const unsigned short* __restrict__ upk,
                unsigned short* hgrp,
                int* flags,
                float* __restrict__ out)
{
  __shared__ __align__(1024) unsigned short Ul[32768];  // 64KB: [ks16][gf4][lane64][8]

  const int tid  = threadIdx.x;
  const int lane = tid & 63;
  const int w    = tid >> 6;
  const int bid  = blockIdx.x;
  const int g    = bid & 7;
  const int hb   = bid >> 3;
  const int d    = g >> 2;
  const int mq   = g & 3;
  const int jl   = lane & 15, q = lane >> 4;

  // ---- stage U slice into LDS (fragment order, linear) ----
  const unsigned short* usrc = upk + (size_t)(d*32 + hb)*32768;
  for (int it = 0; it < 16; ++it){
    int u = it*256 + tid;
    __builtin_amdgcn_global_load_lds(
      (const __attribute__((address_space(1))) void*)(usrc + (size_t)u*8),
      (__attribute__((address_space(3))) void*)(Ul + u*8), 16, 0, 0);
  }

  int* gflags = flags + g*64;                       // 32 used, 256B line per group
  unsigned short* hg = hgrp + (size_t)g*2*32*64*16; // [par][hb][row64][c16]

  float cst[4] = {0.f, 0.f, 0.f, 0.f};

  __syncthreads();  // U staged

  for (int s = 0; s < TT; ++s){
    const int t = d ? (TT-1-s) : s;

    // zx fragments (independent of recurrence — overlap with poll)
    const unsigned short* zbase =
        zxp + ((((((size_t)d*TT + t)*4 + mq)*32 + hb)*4 + w)*64 + lane)*16;
    u16x8 zc0 = *(const u16x8*)(zbase);
    u16x8 zc1 = *(const u16x8*)(zbase + 8);

    // wait for all 32 producers of this group to publish h^(s)
    if (s > 0 && w == 0){
      for (;;){
        int v = (lane < 32)
          ? __hip_atomic_load(&gflags[lane], __ATOMIC_RELAXED, __HIP_MEMORY_SCOPE_AGENT)
          : s;
        if (__all(v >= s)) break;
        __builtin_amdgcn_s_sleep(1);
      }
    }
    __syncthreads();
    asm volatile("" ::: "memory");

    // A-fragments: h^(s)[rows w*16..w*16+15][all 512 h-cols], agent-scope loads
    const char* hgp = (const char*)(hg + (size_t)(s&1)*32*64*16);
    unsigned long long a0[16], a1[16];
    #pragma unroll
    for (int ks = 0; ks < 16; ++ks){
      const unsigned long long* p = (const unsigned long long*)
          (hgp + ((ks*2 + (q>>1))*64 + w*16 + jl)*32 + (q&1)*16);
      a0[ks] = __hip_atomic_load(p,     __ATOMIC_RELAXED, __HIP_MEMORY_SCOPE_AGENT);
      a1[ks] = __hip_atomic_load(p + 1, __ATOMIC_RELAXED, __HIP_MEMORY_SCOPE_AGENT);
    }

    f32x4 acc[4];
    #pragma unroll
    for (int gf = 0; gf < 4; ++gf) acc[gf] = (f32x4){0.f,0.f,0.f,0.f};

    #pragma unroll
    for (int ks = 0; ks < 16; ++ks){
      union { unsigned long long u[2]; bf16x8 v; } af;
      af.u[0] = a0[ks]; af.u[1] = a1[ks];
      #pragma unroll
      for (int gf = 0; gf < 4; ++gf){
        bf16x8 bfr = *(const bf16x8*)(Ul + ((ks*4 + gf)*64 + lane)*8);
        acc[gf] = __builtin_amdgcn_mfma_f32_16x16x32_bf16(af.v, bfr, acc[gf], 0, 0, 0);
      }
    }

    // epilogue: gates, c in regs, write out + h chunk
    unsigned short* hc = hg + (size_t)((((s+1)&1)*32 + hb))*1024;  // [row64][c16]
    #pragma unroll
    for (int rr = 0; rr < 4; ++rr){
      float zi = acc[0][rr] + bf2f((unsigned short)zc0[rr]);
      float zf = acc[1][rr] + bf2f((unsigned short)zc0[4+rr]);
      float zg = acc[2][rr] + bf2f((unsigned short)zc1[rr]);
      float zo = acc[3][rr] + bf2f((unsigned short)zc1[4+rr]);
      float i_ = sigf(zi);
      float f_ = sigf(zf);
      float g_ = tanhfast(zg);
      float o_ = sigf(zo);
      float c  = f_*cst[rr] + i_*g_;
      cst[rr] = c;
      float h = o_*tanhfast(c);

      int row64 = w*16 + q*4 + rr;
      int b = mq*64 + row64;
      out[((size_t)b*TT + t)*(2*HH) + (size_t)d*HH + hb*16 + jl] = h;

      unsigned short h16 = f2bf(h);
      int other = __shfl_xor((int)h16, 1);
      if (!(jl & 1)){
        unsigned int pack = (unsigned int)h16 | (((unsigned int)other & 0xFFFFu) << 16);
        __hip_atomic_store((unsigned int*)(hc + row64*16 + (jl & ~1)),
                           pack, __ATOMIC_RELAXED, __HIP_MEMORY_SCOPE_AGENT);
      }
    }

    asm volatile("s_waitcnt vmcnt(0)" ::: "memory");
    __syncthreads();   // all waves' h stores drained
    if (tid == 0)
      __hip_atomic_store(&gflags[hb], s + 1, __ATOMIC_RELAXED, __HIP_MEMORY_SCOPE_AGENT);
  }
}

// sent_emb[b][n] = word_emb[b][T-1][n] (n<H) or word_emb[b][0][n] (n>=H)
__global__ void final_k(float* __restrict__ out){
  int i = blockIdx.x*blockDim.x + threadIdx.x;
  if (i < BB*2*HH){
    int b = i >> 10;
    int n = i & 1023;
    int t = (n < HH) ? (TT-1) : 0;
    out[(size_t)BB*TT*2*HH + i] = out[((size_t)b*TT + t)*2*HH + n];
  }
}

extern "C" void kernel_launch(void* const* d_in, const int* in_sizes, int n_in,
                              void* d_out, int out_size, void* d_ws, size_t ws_size,
                              hipStream_t stream)
{
  const float* x   = (const float*)d_in[0];
  const float* Wf  = (const float*)d_in[1];
  const float* Uf  = (const float*)d_in[2];
  const float* bf_ = (const float*)d_in[3];
  const float* Wb  = (const float*)d_in[4];
  const float* Ub  = (const float*)d_in[5];
  const float* bb_ = (const float*)d_in[6];
  float* out = (float*)d_out;

  char* ws = (char*)d_ws;
  unsigned short* xtr  = (unsigned short*)(ws);              // 33,554,432 B
  unsigned short* wp   = (unsigned short*)(ws + 33554432);   //  4,194,304 B
  unsigned short* upk  = (unsigned short*)(ws + 37748736);   //  4,194,304 B
  float* bias_pk       = (float*)(ws + 41943040);            //     16,384 B
  unsigned short* hgrp = (unsigned short*)(ws + 41959424);   //  2,097,152 B
  int* flags           = (int*)(ws + 44056576);              //      2,048 B
  unsigned short* zxp  = (unsigned short*)(ws + 50331648);   // 268,435,456 B

  hipMemsetAsync(hgrp, 0, 2097152, stream);
  hipMemsetAsync(flags, 0, 2048, stream);

  prep_x_k   <<<2048, 256, 0, stream>>>(x, xtr);
  prep_w_k   <<<2048, 256, 0, stream>>>(Wf, Wb, wp);
  prep_u_k   <<<2048, 256, 0, stream>>>(Uf, Ub, upk);
  prep_bias_k<<<16,   256, 0, stream>>>(bf_, bb_, bias_pk);

  gemm_xw_k<<<4096, 512, 0, stream>>>(xtr, wp, bias_pk, zxp);

  void* kargs[] = {(void*)&zxp, (void*)&upk, (void*)&hgrp, (void*)&flags, (void*)&out};
  hipLaunchCooperativeKernel((const void*)lstm_seq_k, dim3(256), dim3(256),
                             kargs, 0, stream);

  final_k<<<1024, 256, 0, stream>>>(out);
}